// Round 5
// baseline (542.550 us; speedup 1.0000x reference)
//
#include <hip/hip_runtime.h>

// GCN 3-layer: N=50000, E=800000, dims 128->128->128->64, fp32.
// CSR (counting sort by dst) built once per launch; per layer:
//   gemm (LDS-tiled fp32) -> XCD-column-sliced gather-aggregate.
// Aggregate: feature columns split into 8 groups; group = blockIdx&7 pins each
// group to one XCD (blockIdx round-robins XCDs), so each XCD's gather working
// set is a 3.2MB (F=128) / 1.6MB (F=64) column slice of xw -> L2-resident.
// Wave = one dst node, lanes = [ES edges x C cols], shfl_xor reduce across
// edge-subgroups; self-loop, bias, relu fused. No atomics in hot path.

#define C_IN 128
#define C_HID 128
#define C_OUT 64
#define SCAN_T 256
#define SCAN_ELEMS (SCAN_T * 4)
#define NGRP 8
#define BPG 256   // blocks per column-group (per XCD): 256*256thr = 1.0x CU fill

// ---------------- CSR build ----------------

__global__ void count_deg_kernel(const int* __restrict__ dst, int E, int* __restrict__ degi) {
    int e = blockIdx.x * blockDim.x + threadIdx.x;
    if (e < E) atomicAdd(&degi[dst[e]], 1);
}

// pass 1: per-block (1024 elems) exclusive scan + block totals; also emits dinv.
__global__ void scan1_kernel(const int* __restrict__ degi, int n,
                             int* __restrict__ excl, int* __restrict__ partials,
                             float* __restrict__ dinv) {
    __shared__ int lds[SCAN_T];
    int tid = threadIdx.x;
    int base = blockIdx.x * SCAN_ELEMS + tid * 4;
    int a0 = (base + 0 < n) ? degi[base + 0] : 0;
    int a1 = (base + 1 < n) ? degi[base + 1] : 0;
    int a2 = (base + 2 < n) ? degi[base + 2] : 0;
    int a3 = (base + 3 < n) ? degi[base + 3] : 0;
    if (base + 0 < n) dinv[base + 0] = rsqrtf((float)a0 + 1.0f);
    if (base + 1 < n) dinv[base + 1] = rsqrtf((float)a1 + 1.0f);
    if (base + 2 < n) dinv[base + 2] = rsqrtf((float)a2 + 1.0f);
    if (base + 3 < n) dinv[base + 3] = rsqrtf((float)a3 + 1.0f);
    int t = a0 + a1 + a2 + a3;
    lds[tid] = t;
    __syncthreads();
    for (int off = 1; off < SCAN_T; off <<= 1) {
        int v = (tid >= off) ? lds[tid - off] : 0;
        __syncthreads();
        lds[tid] += v;
        __syncthreads();
    }
    int incl = lds[tid];
    int ex = incl - t;
    if (base + 0 < n) excl[base + 0] = ex;
    if (base + 1 < n) excl[base + 1] = ex + a0;
    if (base + 2 < n) excl[base + 2] = ex + a0 + a1;
    if (base + 3 < n) excl[base + 3] = ex + a0 + a1 + a2;
    if (tid == SCAN_T - 1) partials[blockIdx.x] = incl;
}

__global__ void scan2_kernel(int* __restrict__ partials, int nb) {
    if (threadIdx.x == 0 && blockIdx.x == 0) {
        int run = 0;
        for (int i = 0; i < nb; ++i) { int v = partials[i]; partials[i] = run; run += v; }
    }
}

__global__ void scan3_kernel(int* __restrict__ excl, const int* __restrict__ partials, int n) {
    int gid = blockIdx.x * blockDim.x + threadIdx.x;
    if (gid < n) excl[gid] += partials[gid / SCAN_ELEMS];
}

// fill: atomicAdd directly on rowptr (destructive). After this kernel,
// rowptr[i] == start of row i+1.  csr entry = {src, float_bits(norm)}.
__global__ void fill_csr_kernel(const int* __restrict__ src, const int* __restrict__ dst, int E,
                                const float* __restrict__ dinv, int* __restrict__ rowptr,
                                int2* __restrict__ csr) {
    int e = blockIdx.x * blockDim.x + threadIdx.x;
    if (e >= E) return;
    int s = src[e], d = dst[e];
    int pos = atomicAdd(&rowptr[d], 1);
    float nrm = dinv[s] * dinv[d];
    csr[pos] = make_int2(s, __float_as_int(nrm));
}

// ---------------- GEMM: X[n,128] @ W[128,FOUT] -> Y[n,FOUT] ----------------
template <int FOUT>
__global__ __launch_bounds__(256, 2) void gemm_k128(const float* __restrict__ X,
                                                    const float* __restrict__ W,
                                                    float* __restrict__ Y, int n) {
    constexpr int K = 128;
    constexpr int CT = 64;
    constexpr int MT = 64;
    constexpr int NQ = CT / 4;
    constexpr int RPT = 4;
    __shared__ float Ws[K][CT];
    __shared__ float Xs[MT][K + 4];

    int tid = threadIdx.x;
    int row0 = blockIdx.x * MT;
    int col0 = blockIdx.y * CT;

#pragma unroll
    for (int i = 0; i < (K * CT / 4) / 256; ++i) {
        int idx = tid + i * 256;
        int k = idx / (CT / 4);
        int c = idx % (CT / 4);
        *(float4*)&Ws[k][c * 4] = *(const float4*)(W + (size_t)k * FOUT + col0 + c * 4);
    }
#pragma unroll
    for (int i = 0; i < (MT * K / 4) / 256; ++i) {
        int idx = tid + i * 256;
        int r = idx / (K / 4);
        int c = idx % (K / 4);
        int gr = row0 + r;
        float4 v = (gr < n) ? *(const float4*)(X + (size_t)gr * K + c * 4)
                            : make_float4(0.f, 0.f, 0.f, 0.f);
        *(float4*)&Xs[r][c * 4] = v;
    }
    __syncthreads();

    int cq = tid % NQ;
    int rg = tid / NQ;
    float acc[RPT][4] = {};

    for (int k4 = 0; k4 < K / 4; ++k4) {
        float xa[RPT][4];
#pragma unroll
        for (int r = 0; r < RPT; ++r) {
            float4 t = *(float4*)&Xs[rg * RPT + r][k4 * 4];
            xa[r][0] = t.x; xa[r][1] = t.y; xa[r][2] = t.z; xa[r][3] = t.w;
        }
#pragma unroll
        for (int kk = 0; kk < 4; ++kk) {
            float4 w = *(float4*)&Ws[k4 * 4 + kk][cq * 4];
#pragma unroll
            for (int r = 0; r < RPT; ++r) {
                acc[r][0] = fmaf(xa[r][kk], w.x, acc[r][0]);
                acc[r][1] = fmaf(xa[r][kk], w.y, acc[r][1]);
                acc[r][2] = fmaf(xa[r][kk], w.z, acc[r][2]);
                acc[r][3] = fmaf(xa[r][kk], w.w, acc[r][3]);
            }
        }
    }
#pragma unroll
    for (int r = 0; r < RPT; ++r) {
        int gr = row0 + rg * RPT + r;
        if (gr < n)
            *(float4*)(Y + (size_t)gr * FOUT + col0 + cq * 4) =
                make_float4(acc[r][0], acc[r][1], acc[r][2], acc[r][3]);
    }
}

// ---------------- aggregate batch helper ----------------
// One batch = NI wave-iterations, each covering ES edges (lane layout
// [e_sub x c]).  MASK: clamp edge index into the row, zero the weight.
template <int F, int NI, bool MASK>
__device__ __forceinline__ void agg_batch(const int2* __restrict__ csr, int j, int rem,
                                          const float* __restrict__ xw, int col,
                                          int e_sub, float* acc) {
    constexpr int C = F / NGRP;
    constexpr int ES = 64 / C;
    int s[NI];
    float nm[NI];
#pragma unroll
    for (int t = 0; t < NI; ++t) {
        int eidx = t * ES + e_sub;
        int jj = j + (MASK ? ((eidx < rem) ? eidx : 0) : eidx);
        int2 e = csr[jj];
        s[t] = e.x;
        nm[t] = (!MASK || (eidx < rem)) ? __int_as_float(e.y) : 0.0f;
    }
    float v[NI];
#pragma unroll
    for (int t = 0; t < NI; ++t)
        v[t] = xw[(size_t)s[t] * F + col];
#pragma unroll
    for (int t = 0; t < NI; ++t)
        acc[t & 3] = fmaf(v[t], nm[t], acc[t & 3]);
}

// ------- XCD-sliced aggregate: out = sum_j nrm*xw[src] + xw*dinv^2 + b [+relu] -------
// rowptr is the post-fill shifted array: row i spans [i==0?0:rowptr[i-1], rowptr[i]).
template <int F, bool RELU>
__global__ __launch_bounds__(256, 8) void agg_kernel(const int* __restrict__ rowptr,
                                                     const int2* __restrict__ csr,
                                                     const float* __restrict__ xw,
                                                     const float* __restrict__ dinv,
                                                     const float* __restrict__ bias,
                                                     float* __restrict__ out, int n) {
    constexpr int C = F / NGRP;   // cols per group: 16 (F=128) / 8 (F=64)
    constexpr int ES = 64 / C;    // edges per wave-iteration: 4 / 8
    const int g = blockIdx.x & (NGRP - 1);      // column group == XCD (round-robin)
    const int big = blockIdx.x >> 3;            // block index within group
    const int wave = threadIdx.x >> 6;
    const int lane = threadIdx.x & 63;
    const int e_sub = lane / C;
    const int col = g * C + (lane % C);
    const float bc = bias[col];                 // per-column bias, hoisted
    const int nodeStride = (gridDim.x >> 3) * 4;

    for (int i0 = big * 4 + wave; i0 < n; i0 += nodeStride) {
        int i = __builtin_amdgcn_readfirstlane(i0);
        float di = dinv[i];
        float d2 = di * di;
        int j = (i == 0) ? 0 : rowptr[i - 1];
        int end = rowptr[i];
        j = __builtin_amdgcn_readfirstlane(j);
        end = __builtin_amdgcn_readfirstlane(end);

        float acc[4] = {0.f, 0.f, 0.f, 0.f};
        for (; j + 4 * ES <= end; j += 4 * ES)
            agg_batch<F, 4, false>(csr, j, 0, xw, col, e_sub, acc);
        int rem = end - j;
        if (rem > 0)
            agg_batch<F, 4, true>(csr, j, rem, xw, col, e_sub, acc);

        float r = (acc[0] + acc[1]) + (acc[2] + acc[3]);
#pragma unroll
        for (int off = C; off < 64; off <<= 1)
            r += __shfl_xor(r, off);

        if (lane < C) {
            float o = r + xw[(size_t)i * F + col] * d2 + bc;
            if (RELU) o = fmaxf(o, 0.f);
            out[(size_t)i * F + col] = o;
        }
    }
}

extern "C" void kernel_launch(void* const* d_in, const int* in_sizes, int n_in,
                              void* d_out, int out_size, void* d_ws, size_t ws_size,
                              hipStream_t stream) {
    const float* x  = (const float*)d_in[0];
    const int*   ei = (const int*)d_in[1];
    const float* W1 = (const float*)d_in[2];
    const float* b1 = (const float*)d_in[3];
    const float* W2 = (const float*)d_in[4];
    const float* b2 = (const float*)d_in[5];
    const float* W3 = (const float*)d_in[6];
    const float* b3 = (const float*)d_in[7];
    float* out = (float*)d_out;

    int E = in_sizes[1] / 2;
    int n = in_sizes[0] / C_IN;
    const int* src = ei;
    const int* dst = ei + E;

    // workspace layout (A,B are n*128 floats -> csr is 8B-aligned)
    float* A        = (float*)d_ws;                  // [n*128] xw
    float* B        = A + (size_t)n * C_HID;         // [n*128] h
    int2*  csr      = (int2*)(B + (size_t)n * C_HID);// [E]
    float* dinv     = (float*)(csr + E);             // [n]
    int*   degi     = (int*)(dinv + n);              // [n]
    int*   rowptr   = degi + n;                      // [n+1]
    int*   partials = rowptr + n + 1;                // [<=64]

    int nb = (n + SCAN_ELEMS - 1) / SCAN_ELEMS;

    // ---- CSR build (once; reused by all 3 layers) ----
    hipMemsetAsync(degi, 0, (size_t)n * sizeof(int), stream);
    count_deg_kernel<<<(E + 255) / 256, 256, 0, stream>>>(dst, E, degi);
    scan1_kernel<<<nb, SCAN_T, 0, stream>>>(degi, n, rowptr, partials, dinv);
    scan2_kernel<<<1, 64, 0, stream>>>(partials, nb);
    scan3_kernel<<<(n + 255) / 256, 256, 0, stream>>>(rowptr, partials, n);
    fill_csr_kernel<<<(E + 255) / 256, 256, 0, stream>>>(src, dst, E, dinv, rowptr, csr);

    dim3 g128((n + 63) / 64, C_HID / 64);
    dim3 g64((n + 63) / 64, 1);
    int aggGrid = NGRP * BPG;   // 2048 blocks: 256 per column-group/XCD

    // ---- layer 1 ----
    gemm_k128<C_HID><<<g128, 256, 0, stream>>>(x, W1, A, n);
    agg_kernel<C_HID, false><<<aggGrid, 256, 0, stream>>>(rowptr, csr, A, dinv, b1, B, n);
    // ---- layer 2 ----
    gemm_k128<C_HID><<<g128, 256, 0, stream>>>(B, W2, A, n);
    agg_kernel<C_HID, false><<<aggGrid, 256, 0, stream>>>(rowptr, csr, A, dinv, b2, B, n);
    // ---- layer 3 ----
    gemm_k128<C_OUT><<<g64, 256, 0, stream>>>(B, W3, A, n);
    agg_kernel<C_OUT, true><<<aggGrid, 256, 0, stream>>>(rowptr, csr, A, dinv, b3, out, n);
}

// Round 6
// 489.041 us; speedup vs baseline: 1.1094x; 1.1094x over previous
//
#include <hip/hip_runtime.h>

// GCN 3-layer: N=50000, E=800000, dims 128->128->128->64, fp32.
// CSR (counting sort by dst) built once per launch; per layer:
//   gemm (LDS-tiled fp32) -> per-node wave gather-aggregate (R3 structure:
//   readfirstlane'd node index -> scalar csr reads; 16 row-gathers in flight).
// R4 lesson: XCD column-slicing regresses (csr re-read x8, 8x instr work,
// L2 thrash) -- each XCD pulls ~all of xw once for a random graph; ~190MB
// L2-miss traffic at ~3.5TB/s is the structural wall for agg.
// R5: single-block fused scan (scan1+2+3+dinv) -> 10 dispatches total.

#define C_IN 128
#define C_HID 128
#define C_OUT 64

// ---------------- CSR build ----------------

__global__ void count_deg_kernel(const int* __restrict__ dst, int E, int* __restrict__ degi) {
    int e = blockIdx.x * blockDim.x + threadIdx.x;
    if (e < E) atomicAdd(&degi[dst[e]], 1);
}

// Single-block exclusive scan of degi[0..n) -> rowptr, plus dinv = rsqrt(deg+1).
// 1024 threads; thread t owns a contiguous chunk; LDS Hillis-Steele over totals.
__global__ __launch_bounds__(1024) void scan_all_kernel(const int* __restrict__ degi, int n,
                                                        int* __restrict__ rowptr,
                                                        float* __restrict__ dinv) {
    __shared__ int lds[1024];
    int tid = threadIdx.x;
    int cpt = (n + 1023) >> 10;
    int lo = tid * cpt;
    int hi = min(lo + cpt, n);
    int sum = 0;
    for (int k = lo; k < hi; ++k) sum += degi[k];
    lds[tid] = sum;
    __syncthreads();
    for (int off = 1; off < 1024; off <<= 1) {
        int v = (tid >= off) ? lds[tid - off] : 0;
        __syncthreads();
        lds[tid] += v;
        __syncthreads();
    }
    int ex = lds[tid] - sum;
    for (int k = lo; k < hi; ++k) {
        int d = degi[k];
        rowptr[k] = ex;
        ex += d;
        dinv[k] = rsqrtf((float)d + 1.0f);
    }
}

// fill: atomicAdd directly on rowptr (destructive). After this kernel,
// rowptr[i] == start of row i+1.  csr entry = {src, float_bits(norm)}.
__global__ void fill_csr_kernel(const int* __restrict__ src, const int* __restrict__ dst, int E,
                                const float* __restrict__ dinv, int* __restrict__ rowptr,
                                int2* __restrict__ csr) {
    int e = blockIdx.x * blockDim.x + threadIdx.x;
    if (e >= E) return;
    int s = src[e], d = dst[e];
    int pos = atomicAdd(&rowptr[d], 1);
    float nrm = dinv[s] * dinv[d];
    csr[pos] = make_int2(s, __float_as_int(nrm));
}

// ---------------- GEMM: X[n,128] @ W[128,FOUT] -> Y[n,FOUT] ----------------
template <int FOUT>
__global__ __launch_bounds__(256, 2) void gemm_k128(const float* __restrict__ X,
                                                    const float* __restrict__ W,
                                                    float* __restrict__ Y, int n) {
    constexpr int K = 128;
    constexpr int CT = 64;
    constexpr int MT = 64;
    constexpr int NQ = CT / 4;
    constexpr int RPT = 4;
    __shared__ float Ws[K][CT];
    __shared__ float Xs[MT][K + 4];

    int tid = threadIdx.x;
    int row0 = blockIdx.x * MT;
    int col0 = blockIdx.y * CT;

#pragma unroll
    for (int i = 0; i < (K * CT / 4) / 256; ++i) {
        int idx = tid + i * 256;
        int k = idx / (CT / 4);
        int c = idx % (CT / 4);
        *(float4*)&Ws[k][c * 4] = *(const float4*)(W + (size_t)k * FOUT + col0 + c * 4);
    }
#pragma unroll
    for (int i = 0; i < (MT * K / 4) / 256; ++i) {
        int idx = tid + i * 256;
        int r = idx / (K / 4);
        int c = idx % (K / 4);
        int gr = row0 + r;
        float4 v = (gr < n) ? *(const float4*)(X + (size_t)gr * K + c * 4)
                            : make_float4(0.f, 0.f, 0.f, 0.f);
        *(float4*)&Xs[r][c * 4] = v;
    }
    __syncthreads();

    int cq = tid % NQ;
    int rg = tid / NQ;
    float acc[RPT][4] = {};

    for (int k4 = 0; k4 < K / 4; ++k4) {
        float xa[RPT][4];
#pragma unroll
        for (int r = 0; r < RPT; ++r) {
            float4 t = *(float4*)&Xs[rg * RPT + r][k4 * 4];
            xa[r][0] = t.x; xa[r][1] = t.y; xa[r][2] = t.z; xa[r][3] = t.w;
        }
#pragma unroll
        for (int kk = 0; kk < 4; ++kk) {
            float4 w = *(float4*)&Ws[k4 * 4 + kk][cq * 4];
#pragma unroll
            for (int r = 0; r < RPT; ++r) {
                acc[r][0] = fmaf(xa[r][kk], w.x, acc[r][0]);
                acc[r][1] = fmaf(xa[r][kk], w.y, acc[r][1]);
                acc[r][2] = fmaf(xa[r][kk], w.z, acc[r][2]);
                acc[r][3] = fmaf(xa[r][kk], w.w, acc[r][3]);
            }
        }
    }
#pragma unroll
    for (int r = 0; r < RPT; ++r) {
        int gr = row0 + rg * RPT + r;
        if (gr < n)
            *(float4*)(Y + (size_t)gr * FOUT + col0 + cq * 4) =
                make_float4(acc[r][0], acc[r][1], acc[r][2], acc[r][3]);
    }
}

// ---------------- aggregate helpers (R3 structure) ----------------
// One batch of NB edges: NB wave-uniform csr reads -> NB independent row
// gathers -> FMA into acc[0..3] (unroll-constant indexing).
// MASK: clamp edge index into the row and zero the weight for k >= rem.

template <int NB, bool MASK>
__device__ __forceinline__ void batch_f128(const int2* __restrict__ csr, int j, int rem,
                                           const float* __restrict__ xw, int lane,
                                           float2* acc) {
    int s[NB];
    float nm[NB];
#pragma unroll
    for (int k = 0; k < NB; ++k) {
        int jj = MASK ? (j + ((k < rem) ? k : 0)) : (j + k);
        int2 e = csr[jj];
        s[k] = e.x;
        nm[k] = (!MASK || (k < rem)) ? __int_as_float(e.y) : 0.0f;
    }
    float2 v[NB];
#pragma unroll
    for (int k = 0; k < NB; ++k)
        v[k] = ((const float2*)(xw + (size_t)s[k] * 128))[lane];
#pragma unroll
    for (int k = 0; k < NB; ++k) {
        acc[k & 3].x = fmaf(v[k].x, nm[k], acc[k & 3].x);
        acc[k & 3].y = fmaf(v[k].y, nm[k], acc[k & 3].y);
    }
}

template <int NB, bool MASK>
__device__ __forceinline__ void batch_f64(const int2* __restrict__ csr, int j, int rem,
                                          const float* __restrict__ xw, int lane,
                                          float* acc) {
    int s[NB];
    float nm[NB];
#pragma unroll
    for (int k = 0; k < NB; ++k) {
        int jj = MASK ? (j + ((k < rem) ? k : 0)) : (j + k);
        int2 e = csr[jj];
        s[k] = e.x;
        nm[k] = (!MASK || (k < rem)) ? __int_as_float(e.y) : 0.0f;
    }
    float v[NB];
#pragma unroll
    for (int k = 0; k < NB; ++k)
        v[k] = xw[(size_t)s[k] * 64 + lane];
#pragma unroll
    for (int k = 0; k < NB; ++k)
        acc[k & 3] = fmaf(v[k], nm[k], acc[k & 3]);
}

// ------- fused aggregate: out = sum_j nrm*xw[src] + xw*dinv^2 + b [+relu] -------
// rowptr is the post-fill shifted array: row i spans [i==0?0:rowptr[i-1], rowptr[i]).
template <int F, bool RELU>
__global__ __launch_bounds__(256) void agg_kernel(const int* __restrict__ rowptr,
                                                  const int2* __restrict__ csr,
                                                  const float* __restrict__ xw,
                                                  const float* __restrict__ dinv,
                                                  const float* __restrict__ bias,
                                                  float* __restrict__ out, int n) {
    int wave = threadIdx.x >> 6;
    int lane = threadIdx.x & 63;
    int i0 = blockIdx.x * 4 + wave;
    if (i0 >= n) return;
    // node index is wave-uniform: pin to SGPR so rowptr/csr reads go scalar.
    int i = __builtin_amdgcn_readfirstlane(i0);
    float di = dinv[i];
    float d2 = di * di;
    int j = (i == 0) ? 0 : rowptr[i - 1];
    int end = rowptr[i];
    j = __builtin_amdgcn_readfirstlane(j);
    end = __builtin_amdgcn_readfirstlane(end);

    if constexpr (F == 128) {
        float2 x0 = ((const float2*)(xw + (size_t)i * F))[lane];
        float2 acc[4];
        acc[0].x = x0.x * d2; acc[0].y = x0.y * d2;
        acc[1] = acc[2] = acc[3] = make_float2(0.f, 0.f);

        for (; j + 16 <= end; j += 16) batch_f128<16, false>(csr, j, 0, xw, lane, acc);
        if (j + 8 <= end) { batch_f128<8, false>(csr, j, 0, xw, lane, acc); j += 8; }
        if (j + 4 <= end) { batch_f128<4, false>(csr, j, 0, xw, lane, acc); j += 4; }
        int rem = end - j;
        if (rem > 0) batch_f128<4, true>(csr, j, rem, xw, lane, acc);

        float2 bv = ((const float2*)bias)[lane];
        float2 o;
        o.x = (acc[0].x + acc[1].x) + (acc[2].x + acc[3].x) + bv.x;
        o.y = (acc[0].y + acc[1].y) + (acc[2].y + acc[3].y) + bv.y;
        if (RELU) { o.x = fmaxf(o.x, 0.f); o.y = fmaxf(o.y, 0.f); }
        ((float2*)(out + (size_t)i * F))[lane] = o;
    } else {  // F == 64
        float acc[4];
        acc[0] = xw[(size_t)i * F + lane] * d2;
        acc[1] = acc[2] = acc[3] = 0.f;

        for (; j + 16 <= end; j += 16) batch_f64<16, false>(csr, j, 0, xw, lane, acc);
        if (j + 8 <= end) { batch_f64<8, false>(csr, j, 0, xw, lane, acc); j += 8; }
        if (j + 4 <= end) { batch_f64<4, false>(csr, j, 0, xw, lane, acc); j += 4; }
        int rem = end - j;
        if (rem > 0) batch_f64<4, true>(csr, j, rem, xw, lane, acc);

        float o = (acc[0] + acc[1]) + (acc[2] + acc[3]) + bias[lane];
        if (RELU) o = fmaxf(o, 0.f);
        out[(size_t)i * F + lane] = o;
    }
}

extern "C" void kernel_launch(void* const* d_in, const int* in_sizes, int n_in,
                              void* d_out, int out_size, void* d_ws, size_t ws_size,
                              hipStream_t stream) {
    const float* x  = (const float*)d_in[0];
    const int*   ei = (const int*)d_in[1];
    const float* W1 = (const float*)d_in[2];
    const float* b1 = (const float*)d_in[3];
    const float* W2 = (const float*)d_in[4];
    const float* b2 = (const float*)d_in[5];
    const float* W3 = (const float*)d_in[6];
    const float* b3 = (const float*)d_in[7];
    float* out = (float*)d_out;

    int E = in_sizes[1] / 2;
    int n = in_sizes[0] / C_IN;
    const int* src = ei;
    const int* dst = ei + E;

    // workspace layout (A,B are n*128 floats -> csr is 8B-aligned)
    float* A        = (float*)d_ws;                  // [n*128] xw
    float* B        = A + (size_t)n * C_HID;         // [n*128] h
    int2*  csr      = (int2*)(B + (size_t)n * C_HID);// [E]
    float* dinv     = (float*)(csr + E);             // [n]
    int*   degi     = (int*)(dinv + n);              // [n]
    int*   rowptr   = degi + n;                      // [n+1]

    // ---- CSR build (once; reused by all 3 layers) ----
    hipMemsetAsync(degi, 0, (size_t)n * sizeof(int), stream);
    count_deg_kernel<<<(E + 255) / 256, 256, 0, stream>>>(dst, E, degi);
    scan_all_kernel<<<1, 1024, 0, stream>>>(degi, n, rowptr, dinv);
    fill_csr_kernel<<<(E + 255) / 256, 256, 0, stream>>>(src, dst, E, dinv, rowptr, csr);

    dim3 g128((n + 63) / 64, C_HID / 64);
    dim3 g64((n + 63) / 64, 1);
    int aggBlocks = (n + 3) / 4;

    // ---- layer 1 ----
    gemm_k128<C_HID><<<g128, 256, 0, stream>>>(x, W1, A, n);
    agg_kernel<C_HID, false><<<aggBlocks, 256, 0, stream>>>(rowptr, csr, A, dinv, b1, B, n);
    // ---- layer 2 ----
    gemm_k128<C_HID><<<g128, 256, 0, stream>>>(B, W2, A, n);
    agg_kernel<C_HID, false><<<aggBlocks, 256, 0, stream>>>(rowptr, csr, A, dinv, b2, B, n);
    // ---- layer 3 ----
    gemm_k128<C_OUT><<<g64, 256, 0, stream>>>(B, W3, A, n);
    agg_kernel<C_OUT, true><<<aggBlocks, 256, 0, stream>>>(rowptr, csr, A, dinv, b3, out, n);
}

// Round 7
// 347.402 us; speedup vs baseline: 1.5617x; 1.4077x over previous
//
#include <hip/hip_runtime.h>
#include <hip/hip_fp16.h>

// GCN 3-layer: N=50000, E=800000, dims 128->128->128->64, fp32 in/out.
// CSR (counting sort by dst) built once; per layer:
//   gemm (LDS-tiled fp32, epilogue also emits fp16 copy of xw)
//   -> per-node wave gather-aggregate: neighbor gathers read the fp16 copy
//      (halves the structural 8-XCD x 25.6MB L2-miss gather traffic),
//      self-loop term reads fp32 (protects low-degree nodes), accum fp32.
// R5 lesson: single-block scan = 107us latency trap; back to 3-kernel scan.

#define C_IN 128
#define C_HID 128
#define C_OUT 64
#define SCAN_T 256
#define SCAN_ELEMS (SCAN_T * 4)

// ---------------- CSR build ----------------

__global__ void count_deg_kernel(const int* __restrict__ dst, int E, int* __restrict__ degi) {
    int e = blockIdx.x * blockDim.x + threadIdx.x;
    if (e < E) atomicAdd(&degi[dst[e]], 1);
}

// pass 1: per-block (1024 elems) exclusive scan + block totals; also emits dinv.
__global__ void scan1_kernel(const int* __restrict__ degi, int n,
                             int* __restrict__ excl, int* __restrict__ partials,
                             float* __restrict__ dinv) {
    __shared__ int lds[SCAN_T];
    int tid = threadIdx.x;
    int base = blockIdx.x * SCAN_ELEMS + tid * 4;
    int a0 = (base + 0 < n) ? degi[base + 0] : 0;
    int a1 = (base + 1 < n) ? degi[base + 1] : 0;
    int a2 = (base + 2 < n) ? degi[base + 2] : 0;
    int a3 = (base + 3 < n) ? degi[base + 3] : 0;
    if (base + 0 < n) dinv[base + 0] = rsqrtf((float)a0 + 1.0f);
    if (base + 1 < n) dinv[base + 1] = rsqrtf((float)a1 + 1.0f);
    if (base + 2 < n) dinv[base + 2] = rsqrtf((float)a2 + 1.0f);
    if (base + 3 < n) dinv[base + 3] = rsqrtf((float)a3 + 1.0f);
    int t = a0 + a1 + a2 + a3;
    lds[tid] = t;
    __syncthreads();
    for (int off = 1; off < SCAN_T; off <<= 1) {
        int v = (tid >= off) ? lds[tid - off] : 0;
        __syncthreads();
        lds[tid] += v;
        __syncthreads();
    }
    int incl = lds[tid];
    int ex = incl - t;
    if (base + 0 < n) excl[base + 0] = ex;
    if (base + 1 < n) excl[base + 1] = ex + a0;
    if (base + 2 < n) excl[base + 2] = ex + a0 + a1;
    if (base + 3 < n) excl[base + 3] = ex + a0 + a1 + a2;
    if (tid == SCAN_T - 1) partials[blockIdx.x] = incl;
}

__global__ void scan2_kernel(int* __restrict__ partials, int nb) {
    if (threadIdx.x == 0 && blockIdx.x == 0) {
        int run = 0;
        for (int i = 0; i < nb; ++i) { int v = partials[i]; partials[i] = run; run += v; }
    }
}

__global__ void scan3_kernel(int* __restrict__ excl, const int* __restrict__ partials, int n) {
    int gid = blockIdx.x * blockDim.x + threadIdx.x;
    if (gid < n) excl[gid] += partials[gid / SCAN_ELEMS];
}

// fill: atomicAdd directly on rowptr (destructive). After this kernel,
// rowptr[i] == start of row i+1.  csr entry = {src, float_bits(norm)}.
__global__ void fill_csr_kernel(const int* __restrict__ src, const int* __restrict__ dst, int E,
                                const float* __restrict__ dinv, int* __restrict__ rowptr,
                                int2* __restrict__ csr) {
    int e = blockIdx.x * blockDim.x + threadIdx.x;
    if (e >= E) return;
    int s = src[e], d = dst[e];
    int pos = atomicAdd(&rowptr[d], 1);
    float nrm = dinv[s] * dinv[d];
    csr[pos] = make_int2(s, __float_as_int(nrm));
}

// ------- GEMM: X[n,128] @ W[128,FOUT] -> Y32 (fp32) and Y16 (fp16 copy) -------
template <int FOUT>
__global__ __launch_bounds__(256, 2) void gemm_k128(const float* __restrict__ X,
                                                    const float* __restrict__ W,
                                                    float* __restrict__ Y,
                                                    __half* __restrict__ Yh, int n) {
    constexpr int K = 128;
    constexpr int CT = 64;
    constexpr int MT = 64;
    constexpr int NQ = CT / 4;
    constexpr int RPT = 4;
    __shared__ float Ws[K][CT];
    __shared__ float Xs[MT][K + 4];

    int tid = threadIdx.x;
    int row0 = blockIdx.x * MT;
    int col0 = blockIdx.y * CT;

#pragma unroll
    for (int i = 0; i < (K * CT / 4) / 256; ++i) {
        int idx = tid + i * 256;
        int k = idx / (CT / 4);
        int c = idx % (CT / 4);
        *(float4*)&Ws[k][c * 4] = *(const float4*)(W + (size_t)k * FOUT + col0 + c * 4);
    }
#pragma unroll
    for (int i = 0; i < (MT * K / 4) / 256; ++i) {
        int idx = tid + i * 256;
        int r = idx / (K / 4);
        int c = idx % (K / 4);
        int gr = row0 + r;
        float4 v = (gr < n) ? *(const float4*)(X + (size_t)gr * K + c * 4)
                            : make_float4(0.f, 0.f, 0.f, 0.f);
        *(float4*)&Xs[r][c * 4] = v;
    }
    __syncthreads();

    int cq = tid % NQ;
    int rg = tid / NQ;
    float acc[RPT][4] = {};

    for (int k4 = 0; k4 < K / 4; ++k4) {
        float xa[RPT][4];
#pragma unroll
        for (int r = 0; r < RPT; ++r) {
            float4 t = *(float4*)&Xs[rg * RPT + r][k4 * 4];
            xa[r][0] = t.x; xa[r][1] = t.y; xa[r][2] = t.z; xa[r][3] = t.w;
        }
#pragma unroll
        for (int kk = 0; kk < 4; ++kk) {
            float4 w = *(float4*)&Ws[k4 * 4 + kk][cq * 4];
#pragma unroll
            for (int r = 0; r < RPT; ++r) {
                acc[r][0] = fmaf(xa[r][kk], w.x, acc[r][0]);
                acc[r][1] = fmaf(xa[r][kk], w.y, acc[r][1]);
                acc[r][2] = fmaf(xa[r][kk], w.z, acc[r][2]);
                acc[r][3] = fmaf(xa[r][kk], w.w, acc[r][3]);
            }
        }
    }
#pragma unroll
    for (int r = 0; r < RPT; ++r) {
        int gr = row0 + rg * RPT + r;
        if (gr < n) {
            size_t off = (size_t)gr * FOUT + col0 + cq * 4;
            *(float4*)(Y + off) =
                make_float4(acc[r][0], acc[r][1], acc[r][2], acc[r][3]);
            __half2 h01 = __floats2half2_rn(acc[r][0], acc[r][1]);
            __half2 h23 = __floats2half2_rn(acc[r][2], acc[r][3]);
            uint2 pk = make_uint2(*(unsigned int*)&h01, *(unsigned int*)&h23);
            *(uint2*)(Yh + off) = pk;
        }
    }
}

// ---------------- aggregate helpers ----------------
// One batch of NB edges: NB wave-uniform csr reads -> NB independent fp16 row
// gathers -> fp32 FMA into acc[0..3] (unroll-constant indexing).
// MASK: clamp edge index into the row and zero the weight for k >= rem.

template <int NB, bool MASK>
__device__ __forceinline__ void batch_f128(const int2* __restrict__ csr, int j, int rem,
                                           const __half* __restrict__ xwh, int lane,
                                           float2* acc) {
    int s[NB];
    float nm[NB];
#pragma unroll
    for (int k = 0; k < NB; ++k) {
        int jj = MASK ? (j + ((k < rem) ? k : 0)) : (j + k);
        int2 e = csr[jj];
        s[k] = e.x;
        nm[k] = (!MASK || (k < rem)) ? __int_as_float(e.y) : 0.0f;
    }
    float2 v[NB];
#pragma unroll
    for (int k = 0; k < NB; ++k) {
        __half2 hv = ((const __half2*)(xwh + (size_t)s[k] * 128))[lane];
        v[k] = __half22float2(hv);
    }
#pragma unroll
    for (int k = 0; k < NB; ++k) {
        acc[k & 3].x = fmaf(v[k].x, nm[k], acc[k & 3].x);
        acc[k & 3].y = fmaf(v[k].y, nm[k], acc[k & 3].y);
    }
}

template <int NB, bool MASK>
__device__ __forceinline__ void batch_f64(const int2* __restrict__ csr, int j, int rem,
                                          const __half* __restrict__ xwh, int lane,
                                          float* acc) {
    int s[NB];
    float nm[NB];
#pragma unroll
    for (int k = 0; k < NB; ++k) {
        int jj = MASK ? (j + ((k < rem) ? k : 0)) : (j + k);
        int2 e = csr[jj];
        s[k] = e.x;
        nm[k] = (!MASK || (k < rem)) ? __int_as_float(e.y) : 0.0f;
    }
    float v[NB];
#pragma unroll
    for (int k = 0; k < NB; ++k)
        v[k] = __half2float(xwh[(size_t)s[k] * 64 + lane]);
#pragma unroll
    for (int k = 0; k < NB; ++k)
        acc[k & 3] = fmaf(v[k], nm[k], acc[k & 3]);
}

// ------- fused aggregate: out = sum_j nrm*xw16[src] + xw32*dinv^2 + b [+relu] -------
// rowptr is the post-fill shifted array: row i spans [i==0?0:rowptr[i-1], rowptr[i]).
template <int F, bool RELU>
__global__ __launch_bounds__(256) void agg_kernel(const int* __restrict__ rowptr,
                                                  const int2* __restrict__ csr,
                                                  const float* __restrict__ xw,
                                                  const __half* __restrict__ xwh,
                                                  const float* __restrict__ dinv,
                                                  const float* __restrict__ bias,
                                                  float* __restrict__ out, int n) {
    int wave = threadIdx.x >> 6;
    int lane = threadIdx.x & 63;
    int i0 = blockIdx.x * 4 + wave;
    if (i0 >= n) return;
    // node index is wave-uniform: pin to SGPR so rowptr/csr reads go scalar.
    int i = __builtin_amdgcn_readfirstlane(i0);
    float di = dinv[i];
    float d2 = di * di;
    int j = (i == 0) ? 0 : rowptr[i - 1];
    int end = rowptr[i];
    j = __builtin_amdgcn_readfirstlane(j);
    end = __builtin_amdgcn_readfirstlane(end);

    if constexpr (F == 128) {
        float2 x0 = ((const float2*)(xw + (size_t)i * F))[lane];   // fp32 self-loop
        float2 acc[4];
        acc[0].x = x0.x * d2; acc[0].y = x0.y * d2;
        acc[1] = acc[2] = acc[3] = make_float2(0.f, 0.f);

        for (; j + 16 <= end; j += 16) batch_f128<16, false>(csr, j, 0, xwh, lane, acc);
        if (j + 8 <= end) { batch_f128<8, false>(csr, j, 0, xwh, lane, acc); j += 8; }
        if (j + 4 <= end) { batch_f128<4, false>(csr, j, 0, xwh, lane, acc); j += 4; }
        int rem = end - j;
        if (rem > 0) batch_f128<4, true>(csr, j, rem, xwh, lane, acc);

        float2 bv = ((const float2*)bias)[lane];
        float2 o;
        o.x = (acc[0].x + acc[1].x) + (acc[2].x + acc[3].x) + bv.x;
        o.y = (acc[0].y + acc[1].y) + (acc[2].y + acc[3].y) + bv.y;
        if (RELU) { o.x = fmaxf(o.x, 0.f); o.y = fmaxf(o.y, 0.f); }
        ((float2*)(out + (size_t)i * F))[lane] = o;
    } else {  // F == 64
        float acc[4];
        acc[0] = xw[(size_t)i * F + lane] * d2;                    // fp32 self-loop
        acc[1] = acc[2] = acc[3] = 0.f;

        for (; j + 16 <= end; j += 16) batch_f64<16, false>(csr, j, 0, xwh, lane, acc);
        if (j + 8 <= end) { batch_f64<8, false>(csr, j, 0, xwh, lane, acc); j += 8; }
        if (j + 4 <= end) { batch_f64<4, false>(csr, j, 0, xwh, lane, acc); j += 4; }
        int rem = end - j;
        if (rem > 0) batch_f64<4, true>(csr, j, rem, xwh, lane, acc);

        float o = (acc[0] + acc[1]) + (acc[2] + acc[3]) + bias[lane];
        if (RELU) o = fmaxf(o, 0.f);
        out[(size_t)i * F + lane] = o;
    }
}

extern "C" void kernel_launch(void* const* d_in, const int* in_sizes, int n_in,
                              void* d_out, int out_size, void* d_ws, size_t ws_size,
                              hipStream_t stream) {
    const float* x  = (const float*)d_in[0];
    const int*   ei = (const int*)d_in[1];
    const float* W1 = (const float*)d_in[2];
    const float* b1 = (const float*)d_in[3];
    const float* W2 = (const float*)d_in[4];
    const float* b2 = (const float*)d_in[5];
    const float* W3 = (const float*)d_in[6];
    const float* b3 = (const float*)d_in[7];
    float* out = (float*)d_out;

    int E = in_sizes[1] / 2;
    int n = in_sizes[0] / C_IN;
    const int* src = ei;
    const int* dst = ei + E;

    // workspace layout (A,B n*128 fp32; Ah n*128 fp16; all 8B-aligned)
    float*  A        = (float*)d_ws;                   // [n*128] xw fp32
    float*  B        = A + (size_t)n * C_HID;          // [n*128] h fp32
    __half* Ah       = (__half*)(B + (size_t)n * C_HID); // [n*128] xw fp16
    int2*   csr      = (int2*)(Ah + (size_t)n * C_HID);  // [E]
    float*  dinv     = (float*)(csr + E);              // [n]
    int*    degi     = (int*)(dinv + n);               // [n]
    int*    rowptr   = degi + n;                       // [n+1]
    int*    partials = rowptr + n + 1;                 // [<=64]

    int nb = (n + SCAN_ELEMS - 1) / SCAN_ELEMS;

    // ---- CSR build (once; reused by all 3 layers) ----
    hipMemsetAsync(degi, 0, (size_t)n * sizeof(int), stream);
    count_deg_kernel<<<(E + 255) / 256, 256, 0, stream>>>(dst, E, degi);
    scan1_kernel<<<nb, SCAN_T, 0, stream>>>(degi, n, rowptr, partials, dinv);
    scan2_kernel<<<1, 64, 0, stream>>>(partials, nb);
    scan3_kernel<<<(n + 255) / 256, 256, 0, stream>>>(rowptr, partials, n);
    fill_csr_kernel<<<(E + 255) / 256, 256, 0, stream>>>(src, dst, E, dinv, rowptr, csr);

    dim3 g128((n + 63) / 64, C_HID / 64);
    dim3 g64((n + 63) / 64, 1);
    int aggBlocks = (n + 3) / 4;

    // ---- layer 1 ----
    gemm_k128<C_HID><<<g128, 256, 0, stream>>>(x, W1, A, Ah, n);
    agg_kernel<C_HID, false><<<aggBlocks, 256, 0, stream>>>(rowptr, csr, A, Ah, dinv, b1, B, n);
    // ---- layer 2 ----
    gemm_k128<C_HID><<<g128, 256, 0, stream>>>(B, W2, A, Ah, n);
    agg_kernel<C_HID, false><<<aggBlocks, 256, 0, stream>>>(rowptr, csr, A, Ah, dinv, b2, B, n);
    // ---- layer 3 ----
    gemm_k128<C_OUT><<<g64, 256, 0, stream>>>(B, W3, A, Ah, n);
    agg_kernel<C_OUT, true><<<aggBlocks, 256, 0, stream>>>(rowptr, csr, A, Ah, dinv, b3, out, n);
}